// Round 1
// baseline (779.985 us; speedup 1.0000x reference)
//
#include <hip/hip_runtime.h>
#include <hip/hip_bf16.h>

typedef __attribute__((ext_vector_type(8))) __bf16 bf16x8;
typedef __attribute__((ext_vector_type(4))) __bf16 bf16x4;
typedef __attribute__((ext_vector_type(16))) float f32x16;

#define D_IN   2048
#define D_FF   8192
#define D_OUT  2048
#define BATCH  4096
#define SIZE_N 5794
#define SIZE_M 2897
// padded GEMM1 dims
#define PN 5888   // 23*256
#define PK 2944   // 92*32

#define OFF_B1 16777216
#define OFF_W2 16785408
#define OFF_B2 33562624

#define BK   32
#define NBUF 4

__device__ __forceinline__ void gload_lds16(const __bf16* g, __bf16* lds) {
    __builtin_amdgcn_global_load_lds(
        (const __attribute__((address_space(1))) void*)g,
        (__attribute__((address_space(3))) void*)lds,
        16, 0, 0);
}

template<int N> __device__ __forceinline__ void wait_vmcnt() {
    static_assert(N == 0 || N == 3 || N == 4 || N == 6 || N == 8, "unsupported vmcnt");
    if constexpr (N == 0)      asm volatile("s_waitcnt vmcnt(0)" ::: "memory");
    else if constexpr (N == 3) asm volatile("s_waitcnt vmcnt(3)" ::: "memory");
    else if constexpr (N == 4) asm volatile("s_waitcnt vmcnt(4)" ::: "memory");
    else if constexpr (N == 6) asm volatile("s_waitcnt vmcnt(6)" ::: "memory");
    else                       asm volatile("s_waitcnt vmcnt(8)" ::: "memory");
}
__device__ __forceinline__ void wait_lgkm0() {
    asm volatile("s_waitcnt lgkmcnt(0)" ::: "memory");
}

// C = A (M x K, row-major) * B^T (B is N x K, row-major), bf16 in, fp32 acc.
// Deep-pipelined schedule (T3+T4+T2+T5):
//   - BK=32, NBUF=4 LDS buffers; iteration t computes tile t and stages tile t+3.
//   - Buffer safety: stage(t') at iter t'-3 writes buf[t'&3]; that buffer's previous
//     reader is tile t'-4, whose reads completed (explicit lgkmcnt(0)) before iter
//     t'-4's tail barrier, which precedes iter t'-3. Reader side: tile t's loads are
//     covered by iter t-1's tail vmcnt (counted) + barrier.
//   - Counted vmcnt: steady state leaves 2 tiles (2L loads) in flight across every
//     barrier; waited-for loads were issued 3 iterations earlier (wait ~free).
// LDS row = 32 bf16 = 4 chunks of 16B; chunk c of tile-row r stored at slot
// c ^ ((r>>1)&3). Read: lane (fr,kh) reads slot (2ks+kh) ^ ((fr>>1)&3); any 8
// consecutive lanes hit all 8 bank-quads (g mod 8 = 4*(fr&1) + slot, bijective).
// Staging keeps LDS dest linear (global_load_lds requirement); the swizzle is
// applied by pre-swizzling the per-lane GLOBAL source chunk: (lane&3)^((lane>>3)&3).
// MODE 0: store bf16, bounds-checked, no bias
// MODE 1: +bias, relu, store bf16
// MODE 2: +bias, store fp32
template<int MODE, int BM, int BN>
__global__ __launch_bounds__(512, 2)
void gemm_nt2(const __bf16* __restrict__ A, int lda,
              const __bf16* __restrict__ B, int ldb,
              void* __restrict__ Cv, int ldc,
              const __bf16* __restrict__ bias,
              int K, int Mvalid, int Nvalid)
{
    constexpr int LA = BM / 128;        // A gloads per wave per K-tile (16 rows each)
    constexpr int LB = BN / 128;
    constexpr int L  = LA + LB;         // loads per wave per K-tile
    constexpr int FM = BM / 64;         // 32-row MFMA frags per wave (wave owns BM/2 rows)
    constexpr int FN = BN / 128;        // 32-col MFMA frags per wave (wave owns BN/4 cols)
    constexpr int ROWS = BM + BN;

    __shared__ bf16x8 lds[NBUF * ROWS * 4];   // 128 KB (256x256) / 96 KB (128x256)

    const int tid  = threadIdx.x;
    const int wave = tid >> 6;
    const int lane = tid & 63;

    const int bm0 = blockIdx.x * BM;
    const int bn0 = blockIdx.y * BN;

    const int wm = wave >> 2;           // 0..1
    const int wn = wave & 3;            // 0..3

    // staging: one gload covers 16 rows x 4 slots (1 KB); lane L -> row L>>2,
    // slot L&3, fetching global chunk (L&3) ^ ((L>>3)&3) of its row.
    const int srow   = lane >> 2;                               // 0..15
    const int schunk = ((lane & 3) ^ ((lane >> 3) & 3)) * 8;    // elems

    const __bf16* aS = A + (size_t)(bm0 + wave * (BM / 8) + srow) * lda + schunk;
    const __bf16* bS = B + (size_t)(bn0 + wave * (BN / 8) + srow) * ldb + schunk;

    auto stage = [&](int t) {
        const int bb = t & (NBUF - 1);
        bf16x8* bufA = &lds[bb * ROWS * 4];
        bf16x8* bufB = bufA + BM * 4;
        const size_t kof = (size_t)t * BK;
        #pragma unroll
        for (int i = 0; i < LA; ++i)
            gload_lds16(aS + kof + (size_t)(16 * i) * lda,
                        (__bf16*)&bufA[(wave * (BM / 8) + 16 * i) * 4]);
        #pragma unroll
        for (int i = 0; i < LB; ++i)
            gload_lds16(bS + kof + (size_t)(16 * i) * ldb,
                        (__bf16*)&bufB[(wave * (BN / 8) + 16 * i) * 4]);
    };

    // fragment read coords
    const int fr  = lane & 31;
    const int kh  = lane >> 5;
    const int swz = (fr >> 1) & 3;

    f32x16 acc[FM][FN] = {};

    const int nt = K / BK;   // all callers have nt >= 3

    stage(0); stage(1); stage(2);
    wait_vmcnt<2 * L>();                 // tile 0 landed (tiles 1,2 in flight)
    __builtin_amdgcn_s_barrier();

    for (int t = 0; t < nt; ++t) {
        if (t + 3 < nt) stage(t + 3);    // writes buf[(t+3)&3] = buf[(t-1)&3]: its
                                         // readers (tile t-1) done before prev barrier

        const int bb = t & (NBUF - 1);
        const bf16x8* bufA = &lds[bb * ROWS * 4];
        const bf16x8* bufB = bufA + BM * 4;

        #pragma unroll
        for (int ks = 0; ks < 2; ++ks) {
            const int sl = (2 * ks + kh) ^ swz;
            bf16x8 af[FM], bq[FN];
            #pragma unroll
            for (int m = 0; m < FM; ++m)
                af[m] = bufA[(wm * (BM / 2) + m * 32 + fr) * 4 + sl];
            #pragma unroll
            for (int n = 0; n < FN; ++n)
                bq[n] = bufB[(wn * (BN / 4) + n * 32 + fr) * 4 + sl];
            __builtin_amdgcn_s_setprio(1);
            #pragma unroll
            for (int m = 0; m < FM; ++m) {
                #pragma unroll
                for (int n = 0; n < FN; ++n)
                    acc[m][n] = __builtin_amdgcn_mfma_f32_32x32x16_bf16(
                        af[m], bq[n], acc[m][n], 0, 0, 0);
            }
            __builtin_amdgcn_s_setprio(0);
        }

        if (t + 1 < nt) {
            wait_lgkm0();                        // my reads of buf[t&3] complete
            if      (t + 3 < nt) wait_vmcnt<2 * L>();   // tile t+1 landed; t+2,t+3 in flight
            else if (t + 2 < nt) wait_vmcnt<L>();
            else                 wait_vmcnt<0>();
            __builtin_amdgcn_s_barrier();        // visibility + protects buf[t&3]
        }
    }

    // epilogue: C/D layout col=lane&31, row=(reg&3)+8*(reg>>2)+4*(lane>>5)
    const int ecol = lane & 31;
    const int er0  = 4 * kh;
    #pragma unroll
    for (int m = 0; m < FM; ++m) {
        #pragma unroll
        for (int n = 0; n < FN; ++n) {
            const int colBase = bn0 + wn * (BN / 4) + n * 32 + ecol;
            #pragma unroll
            for (int reg = 0; reg < 16; ++reg) {
                const int row = bm0 + wm * (BM / 2) + m * 32
                              + (reg & 3) + 8 * (reg >> 2) + er0;
                float v = acc[m][n][reg];
                if constexpr (MODE == 0) {
                    if (row < Mvalid && colBase < Nvalid)
                        ((__bf16*)Cv)[(size_t)row * ldc + colBase] = (__bf16)v;
                } else if constexpr (MODE == 1) {
                    v += (float)bias[colBase];
                    v = v > 0.f ? v : 0.f;
                    ((__bf16*)Cv)[(size_t)row * ldc + colBase] = (__bf16)v;
                } else {
                    v += (float)bias[colBase];
                    ((float*)Cv)[(size_t)row * ldc + colBase] = v;
                }
            }
        }
    }
}

// fp32 (rows x cols) -> zero-padded bf16 (prows x pcols), row-major
__global__ void pad_cvt_bf16(const float* __restrict__ in, __bf16* __restrict__ out,
                             int rows, int cols, int pcols, int total)
{
    int idx = blockIdx.x * blockDim.x + threadIdx.x;
    if (idx >= total) return;
    int r = idx / pcols;
    int c = idx - r * pcols;
    float v = (r < rows && c < cols) ? in[(size_t)r * cols + c] : 0.0f;
    out[idx] = (__bf16)v;
}

// straight fp32 -> bf16, vectorized x4
__global__ void cvt_bf16_vec(const float4* __restrict__ in, bf16x4* __restrict__ out, int n4)
{
    int i = blockIdx.x * blockDim.x + threadIdx.x;
    if (i >= n4) return;
    float4 v = in[i];
    bf16x4 o;
    o.x = (__bf16)v.x; o.y = (__bf16)v.y; o.z = (__bf16)v.z; o.w = (__bf16)v.w;
    out[i] = o;
}

extern "C" void kernel_launch(void* const* d_in, const int* in_sizes, int n_in,
                              void* d_out, int out_size, void* d_ws, size_t ws_size,
                              hipStream_t stream)
{
    const float* x  = (const float*)d_in[0];
    const float* V1 = (const float*)d_in[1];
    const float* V2 = (const float*)d_in[2];
    float* out = (float*)d_out;

    char* ws = (char*)d_ws;
    const size_t vbElems  = (size_t)SIZE_N * SIZE_N;   // 33,570,436
    const size_t padElems = (size_t)PN * PK;           // 17,334,272

    size_t off = 0;
    __bf16* Vb = (__bf16*)(ws + off);
    off += ((vbElems * 2 + 255) / 256) * 256;          // 67,141,120
    __bf16* V1b = (__bf16*)(ws + off);                 // live only through GEMM1
    __bf16* V2b = V1b + padElems;
    __bf16* hb  = (__bf16*)(ws + off);                 // overlaps V1b/V2b (live after GEMM1)
    off += ((2 * padElems * 2 + 255) / 256) * 256;     // 69,337,088
    __bf16* xb = (__bf16*)(ws + off);
    off += (size_t)BATCH * D_IN * 2;
    if (ws_size < off) return;  // workspace too small -> fail validation cleanly

    // fp32 -> bf16 conversions (V1/V2 zero-padded to PN x PK)
    {
        int total  = (int)padElems;
        int blocks = (total + 255) / 256;
        pad_cvt_bf16<<<blocks, 256, 0, stream>>>(V1, V1b, SIZE_N, SIZE_M, PK, total);
        pad_cvt_bf16<<<blocks, 256, 0, stream>>>(V2, V2b, SIZE_N, SIZE_M, PK, total);
        int n4 = BATCH * D_IN / 4;
        cvt_bf16_vec<<<(n4 + 255) / 256, 256, 0, stream>>>((const float4*)x, (bf16x4*)xb, n4);
    }

    // GEMM1: V = V1 * V2^T  (padded 5888x5888x2944, store valid 5794x5794 as bf16 flat)
    gemm_nt2<0, 256, 256><<<dim3(PN / 256, PN / 256), 512, 0, stream>>>(
        V1b, PK, V2b, PK, (void*)Vb, SIZE_N, (const __bf16*)nullptr, PK, SIZE_N, SIZE_N);

    // GEMM2: h = relu(x * W1^T + b1)   (4096 x 8192 x 2048)
    gemm_nt2<1, 256, 256><<<dim3(BATCH / 256, D_FF / 256), 512, 0, stream>>>(
        xb, D_IN, Vb, D_IN, (void*)hb, D_FF, Vb + OFF_B1, D_IN, BATCH, D_FF);

    // GEMM3: out = h * W2^T + b2       (4096 x 2048 x 8192)
    // 128x256 tile -> grid 32x8 = 256 blocks (256x256 would leave half the CUs idle)
    gemm_nt2<2, 128, 256><<<dim3(BATCH / 128, D_OUT / 256), 512, 0, stream>>>(
        hb, D_FF, Vb + OFF_W2, D_FF, (void*)out, D_OUT, Vb + OFF_B2, D_FF, BATCH, D_OUT);
}